// Round 1
// baseline (30335.770 us; speedup 1.0000x reference)
//
#include <hip/hip_runtime.h>
#include <hip/hip_bf16.h>
#include <math.h>

// Problem constants (match the JAX reference)
#define BB   64      // batch
#define TT   512     // time steps
#define CIN  32      // signal features
#define THF  32      // interval features
#define HH   1024    // hidden
#define LL   128     // output logits
#define INF  64      // CIN + THF
#define KD   1088    // INF + HH  (rows of W_rnn)

// One workgroup per batch element. 512 threads, each owns 2 hidden units
// (columns 2*tid, 2*tid+1 of W_rnn) -> float2 coalesced weight loads.
// h (and current input features) live in LDS; recurrence via __syncthreads.
__global__ __launch_bounds__(512)
void rnn_scan_kernel(const float* __restrict__ x,     // [B, T, CIN]
                     const float* __restrict__ tf,    // [B, T, THF]
                     const float* __restrict__ W,     // [KD, HH] row-major
                     const float* __restrict__ bias,  // [HH]
                     const float* __restrict__ Wout,  // [HH, LL] row-major
                     const float* __restrict__ bout,  // [LL]
                     float* __restrict__ out)         // [B, 1, LL]
{
    __shared__ float s[KD];            // s[0..63] = [x_t, t_t], s[64..1087] = h
    const int b_idx = blockIdx.x;
    const int tid   = threadIdx.x;

    // ---- init: step-0 inputs + h = 0 ----
    if (tid < CIN) {
        s[tid] = x[b_idx * TT * CIN + tid];
    } else if (tid < INF) {
        s[tid] = tf[b_idx * TT * THF + (tid - CIN)];
    }
    for (int i = tid; i < HH; i += 512) s[INF + i] = 0.0f;
    __syncthreads();

    const int j0 = tid * 2;
    const float bias0 = bias[j0];
    const float bias1 = bias[j0 + 1];

    for (int t = 0; t < TT; ++t) {
        float z0 = bias0;
        float z1 = bias1;

        // z[j] = bias[j] + sum_k s[k] * W[k][j]
        #pragma unroll 8
        for (int k = 0; k < KD; ++k) {
            const float2 w = *reinterpret_cast<const float2*>(&W[k * HH + j0]);
            const float sv = s[k];
            z0 = fmaf(sv, w.x, z0);
            z1 = fmaf(sv, w.y, z1);
        }

        // prefetch next step's input features into registers
        float nin = 0.0f;
        const int tn = t + 1;
        if (tn < TT) {
            if (tid < CIN)      nin = x[b_idx * TT * CIN + tn * CIN + tid];
            else if (tid < INF) nin = tf[b_idx * TT * THF + tn * THF + (tid - CIN)];
        }

        __syncthreads();                       // all reads of s done
        s[INF + j0]     = tanhf(z0);
        s[INF + j0 + 1] = tanhf(z1);
        if (tid < INF && tn < TT) s[tid] = nin;
        __syncthreads();                       // new h visible
    }

    // ---- epilogue: out[b, l] = bias_out[l] + sum_j h[j] * Wout[j][l] ----
    for (int l = tid; l < LL; l += 512) {
        float acc = bout[l];
        for (int j = 0; j < HH; ++j) {
            acc = fmaf(s[INF + j], Wout[j * LL + l], acc);
        }
        out[b_idx * LL + l] = acc;
    }
}

extern "C" void kernel_launch(void* const* d_in, const int* in_sizes, int n_in,
                              void* d_out, int out_size, void* d_ws, size_t ws_size,
                              hipStream_t stream) {
    const float* x    = (const float*)d_in[0];   // [64, 512, 32]
    const float* tf   = (const float*)d_in[1];   // [64, 512, 32]
    const float* W    = (const float*)d_in[2];   // [1088, 1024]
    const float* brnn = (const float*)d_in[3];   // [1024]
    const float* Wout = (const float*)d_in[4];   // [1024, 128]
    const float* bout = (const float*)d_in[5];   // [128]
    float* out = (float*)d_out;                  // [64, 1, 128]

    rnn_scan_kernel<<<BB, 512, 0, stream>>>(x, tf, W, brnn, Wout, bout, out);
}

// Round 2
// 5923.533 us; speedup vs baseline: 5.1212x; 5.1212x over previous
//
#include <hip/hip_runtime.h>
#include <math.h>

#define BB   64      // batch
#define TT   512     // time steps
#define CIN  32      // signal features
#define THF  32      // interval features
#define HH   1024    // hidden
#define LL   128     // output logits
#define INF  64      // CIN + THF
#define KD   1088    // INF + HH
#define SROW 1092    // padded LDS row stride (floats): 1092%32=4 -> b128 reads conflict-free

// ---------------- W transpose: W[KD][HH] -> Wt[HH][KD] ----------------
__global__ __launch_bounds__(256)
void transposeW(const float* __restrict__ W, float* __restrict__ Wt) {
    __shared__ float tile[32][33];
    const int nt = blockIdx.x * 32;   // 0..1023
    const int kt = blockIdx.y * 32;   // 0..1087
    for (int i = threadIdx.y; i < 32; i += 8)
        tile[i][threadIdx.x] = W[(size_t)(kt + i) * HH + nt + threadIdx.x];
    __syncthreads();
    for (int i = threadIdx.y; i < 32; i += 8)
        Wt[(size_t)(nt + i) * KD + kt + threadIdx.x] = tile[threadIdx.x][i];
}

// ---------------- per-step kernel ----------------
// grid = 256 wgs: bid = bg*32 + cg.  bg: 8 batches, cg: 32 hidden columns.
// bid%8 == cg%8 -> same-column wgs land on the same XCD (L2-resident W slice).
__global__ __launch_bounds__(256)
void rnn_step(const float* __restrict__ x, const float* __restrict__ tfeat,
              const float* __restrict__ Wt,    // [HH][KD]
              const float* __restrict__ bias,  // [HH]
              const float* __restrict__ hprev, // [BB][HH]
              float* __restrict__ hnext,       // [BB][HH]
              int t)
{
    __shared__ float s[8 * SROW];
    __shared__ float zbuf[8][33];
    const int tid = threadIdx.x;
    const int bid = blockIdx.x;
    const int bg = bid >> 5;      // 0..7
    const int cg = bid & 31;      // 0..31

    // ---- stage h_prev: 8 batches x 1024 floats, coalesced float4 ----
    {
        const int b = tid >> 5;   // 0..7
        const int c = tid & 31;   // 0..31
        const float4* src = reinterpret_cast<const float4*>(hprev + (size_t)(bg*8 + b) * HH);
        float* dst = s + b * SROW + INF;
        #pragma unroll
        for (int i = 0; i < 8; ++i) {
            float4 v = src[c + 32*i];
            *reinterpret_cast<float4*>(dst + 4*(c + 32*i)) = v;
        }
    }
    // ---- stage step-t input features: [x_t(32); t_t(32)] per batch ----
    if (tid < 128) {
        const int b = tid >> 4;          // 0..7
        const int j = (tid & 15) * 4;    // 0,4,...,60
        float4 v;
        if (j < CIN) v = *reinterpret_cast<const float4*>(x     + ((size_t)(bg*8 + b)*TT + t)*CIN + j);
        else         v = *reinterpret_cast<const float4*>(tfeat + ((size_t)(bg*8 + b)*TT + t)*THF + (j - CIN));
        *reinterpret_cast<float4*>(s + b*SROW + j) = v;
    }
    __syncthreads();

    // lane -> (batch, column): 8 lanes share a column (LDS broadcast on s),
    // 8 distinct columns per wave (coalesced 16B W reads, 128B/instr).
    const int w  = tid >> 6;
    const int l  = tid & 63;
    const int nl = w*8 + (l >> 3);   // 0..31
    const int b  = l & 7;
    const int n  = cg*32 + nl;
    const float* wcol = Wt + (size_t)n * KD;
    const float* srow = s + b * SROW;

    float a0 = 0.f, a1 = 0.f, a2 = 0.f, a3 = 0.f;   // 4 accs: break fmac dep chain
    #pragma unroll 2
    for (int k = 0; k < KD; k += 8) {
        float4 s0 = *reinterpret_cast<const float4*>(srow + k);
        float4 s1 = *reinterpret_cast<const float4*>(srow + k + 4);
        float4 w0 = *reinterpret_cast<const float4*>(wcol + k);
        float4 w1 = *reinterpret_cast<const float4*>(wcol + k + 4);
        a0 = fmaf(s0.x, w0.x, a0);
        a1 = fmaf(s0.y, w0.y, a1);
        a2 = fmaf(s0.z, w0.z, a2);
        a3 = fmaf(s0.w, w0.w, a3);
        a0 = fmaf(s1.x, w1.x, a0);
        a1 = fmaf(s1.y, w1.y, a1);
        a2 = fmaf(s1.z, w1.z, a2);
        a3 = fmaf(s1.w, w1.w, a3);
    }
    const float z = (a0 + a1) + (a2 + a3) + bias[n];
    zbuf[b][nl] = tanhf(z);
    __syncthreads();

    // coalesced h_next write: 32 consecutive floats per 32-thread group
    {
        const int ob = tid >> 5;
        const int on = tid & 31;
        hnext[(size_t)(bg*8 + ob) * HH + cg*32 + on] = zbuf[ob][on];
    }
}

// ---------------- epilogue: out[b][l] = b_out[l] + h[b] . W_out[:,l] ----------------
__global__ __launch_bounds__(128)
void rnn_out(const float* __restrict__ h,     // [BB][HH] (final h)
             const float* __restrict__ Wout,  // [HH][LL]
             const float* __restrict__ bout,  // [LL]
             float* __restrict__ out)         // [BB][LL]
{
    __shared__ float hl[HH];
    const int b = blockIdx.x, tid = threadIdx.x;
    for (int i = tid; i < HH/4; i += 128)
        *reinterpret_cast<float4*>(hl + 4*i) =
            *reinterpret_cast<const float4*>(h + (size_t)b*HH + 4*i);
    __syncthreads();
    float a0 = bout[tid], a1 = 0.f, a2 = 0.f, a3 = 0.f;
    for (int j = 0; j < HH; j += 4) {
        a0 = fmaf(hl[j+0], Wout[(size_t)(j+0)*LL + tid], a0);
        a1 = fmaf(hl[j+1], Wout[(size_t)(j+1)*LL + tid], a1);
        a2 = fmaf(hl[j+2], Wout[(size_t)(j+2)*LL + tid], a2);
        a3 = fmaf(hl[j+3], Wout[(size_t)(j+3)*LL + tid], a3);
    }
    out[(size_t)b*LL + tid] = (a0 + a1) + (a2 + a3);
}

// ---------------- fallback (round-1 kernel) if ws is too small ----------------
__global__ __launch_bounds__(512)
void rnn_scan_kernel(const float* __restrict__ x, const float* __restrict__ tf,
                     const float* __restrict__ W, const float* __restrict__ bias,
                     const float* __restrict__ Wout, const float* __restrict__ bout,
                     float* __restrict__ out)
{
    __shared__ float s[KD];
    const int b_idx = blockIdx.x, tid = threadIdx.x;
    if (tid < CIN)      s[tid] = x[b_idx * TT * CIN + tid];
    else if (tid < INF) s[tid] = tf[b_idx * TT * THF + (tid - CIN)];
    for (int i = tid; i < HH; i += 512) s[INF + i] = 0.0f;
    __syncthreads();
    const int j0 = tid * 2;
    const float bias0 = bias[j0], bias1 = bias[j0 + 1];
    for (int t = 0; t < TT; ++t) {
        float z0 = bias0, z1 = bias1;
        #pragma unroll 8
        for (int k = 0; k < KD; ++k) {
            const float2 w = *reinterpret_cast<const float2*>(&W[(size_t)k * HH + j0]);
            const float sv = s[k];
            z0 = fmaf(sv, w.x, z0);
            z1 = fmaf(sv, w.y, z1);
        }
        float nin = 0.0f;
        const int tn = t + 1;
        if (tn < TT) {
            if (tid < CIN)      nin = x[b_idx * TT * CIN + tn * CIN + tid];
            else if (tid < INF) nin = tf[b_idx * TT * THF + tn * THF + (tid - CIN)];
        }
        __syncthreads();
        s[INF + j0]     = tanhf(z0);
        s[INF + j0 + 1] = tanhf(z1);
        if (tid < INF && tn < TT) s[tid] = nin;
        __syncthreads();
    }
    for (int lll = tid; lll < LL; lll += 512) {
        float acc = bout[lll];
        for (int j = 0; j < HH; ++j) acc = fmaf(s[INF + j], Wout[(size_t)j * LL + lll], acc);
        out[(size_t)b_idx * LL + lll] = acc;
    }
}

extern "C" void kernel_launch(void* const* d_in, const int* in_sizes, int n_in,
                              void* d_out, int out_size, void* d_ws, size_t ws_size,
                              hipStream_t stream) {
    const float* x    = (const float*)d_in[0];   // [64, 512, 32]
    const float* tf   = (const float*)d_in[1];   // [64, 512, 32]
    const float* W    = (const float*)d_in[2];   // [1088, 1024]
    const float* brnn = (const float*)d_in[3];   // [1024]
    const float* Wout = (const float*)d_in[4];   // [1024, 128]
    const float* bout = (const float*)d_in[5];   // [128]
    float* out = (float*)d_out;                  // [64, 1, 128]

    const size_t hbuf_elems = 2ull * BB * HH;
    const size_t need = (hbuf_elems + (size_t)HH * KD) * sizeof(float);
    if (ws_size < need) {
        // not enough scratch: correct (slow) fallback
        rnn_scan_kernel<<<BB, 512, 0, stream>>>(x, tf, W, brnn, Wout, bout, out);
        return;
    }

    float* hbuf = (float*)d_ws;                  // [2][BB][HH] ping-pong
    float* Wt   = hbuf + hbuf_elems;             // [HH][KD]

    hipMemsetAsync(hbuf, 0, (size_t)BB * HH * sizeof(float), stream);  // h_0 = 0
    transposeW<<<dim3(HH/32, KD/32), dim3(32, 8), 0, stream>>>(W, Wt);

    for (int t = 0; t < TT; ++t) {
        rnn_step<<<256, 256, 0, stream>>>(x, tf, Wt, brnn,
                                          hbuf + (size_t)(t & 1) * BB * HH,
                                          hbuf + (size_t)((t + 1) & 1) * BB * HH,
                                          t);
    }
    rnn_out<<<BB, 128, 0, stream>>>(hbuf /* parity 0 after step 511 */, Wout, bout, out);
}